// Round 1
// baseline (372.938 us; speedup 1.0000x reference)
//
#include <hip/hip_runtime.h>
#include <math.h>

#define DFEAT 128
#define CHUNK 256   // rows per 256-thread block -> 2048 blocks at TOTAL=524288

// Layout: 16 lanes per row, 8 floats (2x float4) per lane.
// Each wave64 handles 4 rows per iteration; each 16-lane group owns a row
// stream (stride 16 rows) and carries (cur_a, run, cached anchor frag) in
// registers. segment_ids are sorted, so anchor changes are rare (~1/512 rows):
// anchor reload + global atomic flush happen only on change + once at end.
__global__ __launch_bounds__(256) void icc_dist_kernel(
    const float* __restrict__ anchors,
    const float* __restrict__ Xn,
    const int*   __restrict__ seg,
    float*       __restrict__ per_anchor,  // [num_anchors] global accumulator
    int total)
{
    const int tid  = threadIdx.x;
    const int wave = tid >> 6;        // 0..3
    const int lane = tid & 63;
    const int g    = lane >> 4;       // 16-lane group id within wave, 0..3
    const int lr   = lane & 15;       // lane within group
    const int base = blockIdx.x * CHUNK + wave * 4 + g;  // group's first row
    const float eps = 1e-4f / (float)DFEAT;

    int    cur_a = -1;
    float  run   = 0.0f;
    float4 av0 = make_float4(0.f, 0.f, 0.f, 0.f);
    float4 av1 = make_float4(0.f, 0.f, 0.f, 0.f);

    #pragma unroll 2
    for (int i = 0; i < CHUNK / 16; ++i) {
        const int row = base + i * 16;
        if (row < total) {
            const int a = seg[row];       // uniform within 16-lane group
            if (a != cur_a) {             // group-uniform branch, rare
                if (lr == 0 && cur_a >= 0)
                    atomicAdd(&per_anchor[cur_a], run);
                run   = 0.0f;
                cur_a = a;
                const float* ap = anchors + (size_t)a * DFEAT + lr * 8;
                av0 = *reinterpret_cast<const float4*>(ap);
                av1 = *reinterpret_cast<const float4*>(ap + 4);
            }
            const float* xp = Xn + (size_t)row * DFEAT + lr * 8;
            const float4 x0 = *reinterpret_cast<const float4*>(xp);
            const float4 x1 = *reinterpret_cast<const float4*>(xp + 4);
            float d, sq;
            d = x0.x - av0.x; sq  = d * d;
            d = x0.y - av0.y; sq += d * d;
            d = x0.z - av0.z; sq += d * d;
            d = x0.w - av0.w; sq += d * d;
            d = x1.x - av1.x; sq += d * d;
            d = x1.y - av1.y; sq += d * d;
            d = x1.z - av1.z; sq += d * d;
            d = x1.w - av1.w; sq += d * d;
            #pragma unroll
            for (int off = 8; off > 0; off >>= 1)   // stays within 16-lane group
                sq += __shfl_xor(sq, off);
            run += sqrtf(sq + eps);                  // uniform across group
        }
    }
    if (lr == 0 && cur_a >= 0)
        atomicAdd(&per_anchor[cur_a], run);
}

__global__ __launch_bounds__(256) void icc_final_kernel(
    const float* __restrict__ per_anchor,
    float*       __restrict__ out,
    int num_anchors, float inv_total)
{
    __shared__ float red[4];
    const int tid = threadIdx.x;
    float s = 0.0f;
    for (int i = tid; i < num_anchors; i += 256)
        s += log1pf(per_anchor[i]);
    #pragma unroll
    for (int off = 32; off > 0; off >>= 1)
        s += __shfl_down(s, off, 64);
    if ((tid & 63) == 0) red[tid >> 6] = s;
    __syncthreads();
    if (tid == 0) {
        const float t = red[0] + red[1] + red[2] + red[3];
        out[0] = t * inv_total;
    }
}

extern "C" void kernel_launch(void* const* d_in, const int* in_sizes, int n_in,
                              void* d_out, int out_size, void* d_ws, size_t ws_size,
                              hipStream_t stream) {
    const float* anchors = (const float*)d_in[0];
    const float* Xn      = (const float*)d_in[1];
    const int*   seg     = (const int*)d_in[2];
    float* out = (float*)d_out;

    const int num_anchors = in_sizes[0] / DFEAT;   // 1024
    const int total       = in_sizes[2];           // 524288

    float* per_anchor = (float*)d_ws;              // num_anchors floats
    hipMemsetAsync(per_anchor, 0, (size_t)num_anchors * sizeof(float), stream);

    const int blocks = (total + CHUNK - 1) / CHUNK;
    icc_dist_kernel<<<blocks, 256, 0, stream>>>(
        anchors, Xn, seg, per_anchor, total);
    icc_final_kernel<<<1, 256, 0, stream>>>(
        per_anchor, out, num_anchors, 1.0f / (float)total);
}